// Round 6
// baseline (53.951 us; speedup 1.0000x reference)
//
#include <hip/hip_runtime.h>
#include <math.h>

#define BLK 512         // threads per block (8 waves)
#define GSZ 8           // checkpoints (m values) per chunk
#define PAD 4           // float4-overrun padding on k-arrays
#define KSTRIDE (BLK*4) // elements covered per loop sweep (2048)
#define DIAG_REPS 3     // extra dummy passes for profiling visibility

#if __has_builtin(__builtin_amdgcn_rsqf)
#define RSQF(x) __builtin_amdgcn_rsqf(x)
#else
#define RSQF(x) (1.0f / sqrtf(x))
#endif

// fast x^e for x>0 via hw exp2/log2 (~1e-6 rel err, vs 0.176 abs budget)
__device__ __forceinline__ float fast_pow(float x, float e) {
  return __expf(e * __logf(x));
}

// ---------------------------------------------------------------------------
// Precompute (T+PAD elements):
//   cpw[k] = C * lrs[k]^(-gamma)          (k>=1)
//   dd[k]  = 1 - cpw[k]*lr_sum[k-1]       so inner = fma(cpw, Ssum, dd)
//   gapp[k] = lr_gap[k]                   (padded copy, zero beyond T)
// ---------------------------------------------------------------------------
__global__ __launch_bounds__(256) void precompute_kernel(
    const float* __restrict__ lrs, const float* __restrict__ lr_sum,
    const float* __restrict__ lr_gap,
    float* __restrict__ cpw, float* __restrict__ dd, float* __restrict__ gapp,
    const float* __restrict__ gamma_p, const float* __restrict__ C_p, int T) {
  int i = blockIdx.x * 256 + threadIdx.x;
  if (i >= T + PAD) return;
  if (i == 0 || i >= T) {
    cpw[i] = 0.0f; dd[i] = 1.0f; gapp[i] = 0.0f;
    return;
  }
  float c = C_p[0] * fast_pow(lrs[i], -gamma_p[0]);
  cpw[i]  = c;
  dd[i]   = fmaf(-c, lr_sum[i - 1], 1.0f);
  gapp[i] = lr_gap[i];
}

// ---------------------------------------------------------------------------
// Inner body: acc[j] += sum_k gapp[k] * inner(k, Ss[j])^-beta over one chunk.
// Phase 1 unmasked (k <= smin); phase 2 masked, select on p AFTER the
// transcendental (0*NaN poison — round-2 bug).
// ---------------------------------------------------------------------------
template <bool USE_RSQ>
__device__ __forceinline__ void ld_body(
    const float* __restrict__ cpw, const float* __restrict__ dd,
    const float* __restrict__ gapp,
    const float (&Ss)[GSZ], const int (&sv)[GSZ], float (&acc)[GSZ],
    int kEnd1, int smax, float nb) {
  int tid = threadIdx.x;

  for (int k0 = tid * 4; k0 < kEnd1; k0 += KSTRIDE) {
    float4 c4 = *(const float4*)(cpw + k0);
    float4 d4 = *(const float4*)(dd + k0);
    float4 g4 = *(const float4*)(gapp + k0);
    const float ce[4] = {c4.x, c4.y, c4.z, c4.w};
    const float de[4] = {d4.x, d4.y, d4.z, d4.w};
    const float ge[4] = {g4.x, g4.y, g4.z, g4.w};
#pragma unroll
    for (int e = 0; e < 4; ++e) {
#pragma unroll
      for (int j = 0; j < GSZ; ++j) {
        float inner = fmaf(ce[e], Ss[j], de[e]);   // >= 1 here
        float p = USE_RSQ ? RSQF(inner) : __expf(nb * __logf(inner));
        acc[j] = fmaf(ge[e], p, acc[j]);
      }
    }
  }

  for (int k0 = kEnd1 + tid * 4; k0 <= smax; k0 += KSTRIDE) {
    float4 c4 = *(const float4*)(cpw + k0);
    float4 d4 = *(const float4*)(dd + k0);
    float4 g4 = *(const float4*)(gapp + k0);
    const float ce[4] = {c4.x, c4.y, c4.z, c4.w};
    const float de[4] = {d4.x, d4.y, d4.z, d4.w};
    const float ge[4] = {g4.x, g4.y, g4.z, g4.w};
#pragma unroll
    for (int e = 0; e < 4; ++e) {
#pragma unroll
      for (int j = 0; j < GSZ; ++j) {
        float inner = fmaf(ce[e], Ss[j], de[e]);   // may be <= 0 if masked
        float p = USE_RSQ ? RSQF(inner) : __expf(nb * __logf(inner));
        float pm = (k0 + e <= sv[j]) ? p : 0.0f;   // select AFTER computing p
        acc[j] = fmaf(ge[e], pm, acc[j]);
      }
    }
  }
}

// ---------------------------------------------------------------------------
// Process one chunk. DIAGNOSTIC: after the real ld_body pass, run DIAG_REPS
// dummy passes on perturbed Ss (defeats CSE) and keep results live via asm
// sinks (defeats DCE). Output identical; inner-loop time/counters ~4x.
// ---------------------------------------------------------------------------
template <bool USE_RSQ>
__device__ __forceinline__ void process_chunk(
    int chunk,
    const float* __restrict__ S1, const int* __restrict__ step,
    const float* __restrict__ loss, const float* __restrict__ lrs,
    const float* __restrict__ cpw, const float* __restrict__ dd,
    const float* __restrict__ gapp,
    float L0, float A, float alpha, float B, float nb,
    float (&wacc)[BLK / 64][GSZ], float* __restrict__ hub) {
  int mbase = chunk * GSZ;

  float Ss[GSZ]; int sv[GSZ]; float acc[GSZ];
#pragma unroll
  for (int j = 0; j < GSZ; ++j) {
    Ss[j] = S1[mbase + j];
    sv[j] = step[mbase + j];
    acc[j] = 0.0f;
  }
  int smin = sv[0], smax = sv[0];
#pragma unroll
  for (int j = 1; j < GSZ; ++j) {
    smin = min(smin, sv[j]);
    smax = max(smax, sv[j]);
  }
  int kEnd1 = ((smin + 1) / KSTRIDE) * KSTRIDE;

  ld_body<USE_RSQ>(cpw, dd, gapp, Ss, sv, acc, kEnd1, smax, nb);

  // ---- diagnostic dummy passes (profiling only; results sunk, not used) ----
#pragma unroll
  for (int rep = 1; rep <= DIAG_REPS; ++rep) {
    float Ssd[GSZ]; float accD[GSZ];
#pragma unroll
    for (int j = 0; j < GSZ; ++j) {
      Ssd[j] = fmaf((float)rep, 1e-30f, Ss[j]);  // distinct inputs: no CSE
      accD[j] = 0.0f;
    }
    ld_body<USE_RSQ>(cpw, dd, gapp, Ssd, sv, accD, kEnd1, smax, nb);
#pragma unroll
    for (int j = 0; j < GSZ; ++j)
      asm volatile("" : : "v"(accD[j]));          // keep live: no DCE
  }
  // --------------------------------------------------------------------------

  int lane = threadIdx.x & 63, wid = threadIdx.x >> 6;
#pragma unroll
  for (int j = 0; j < GSZ; ++j) {
    float v = acc[j];
#pragma unroll
    for (int off = 32; off; off >>= 1) v += __shfl_down(v, off, 64);
    if (lane == 0) wacc[wid][j] = v;
  }
  __syncthreads();

  if (threadIdx.x < GSZ) {
    int j = threadIdx.x;
    int m = mbase + j;
    float sgp = 0.0f;
#pragma unroll
    for (int w = 0; w < BLK / 64; ++w) sgp += wacc[w][j];
    int s = step[m];
    float Ssum = S1[m];
    float LD = (lrs[0] - lrs[s]) - sgp;   // telescoped gap sum
    float pred = L0 + A * fast_pow(Ssum, -alpha) + B * LD;
    pred = fmaxf(pred, 1e-10f);
    float r = __logf(loss[m]) - __logf(pred);
    float a = fabsf(r);
    const float dlt = 0.001f;
    hub[m] = (a <= dlt) ? (0.5f * r * r) : (dlt * (a - 0.5f * dlt));
  }
  __syncthreads();
}

// ---------------------------------------------------------------------------
// Main: block b handles chunks b and (nchunk-1-b) -> equal work per block.
// ---------------------------------------------------------------------------
__global__ __launch_bounds__(BLK, 4) void ld_kernel(
    const float* __restrict__ S1, const int* __restrict__ step,
    const float* __restrict__ loss, const float* __restrict__ lrs,
    const float* __restrict__ cpw, const float* __restrict__ dd,
    const float* __restrict__ gapp,
    const float* __restrict__ L0_p, const float* __restrict__ A_p,
    const float* __restrict__ alpha_p, const float* __restrict__ B_p,
    const float* __restrict__ beta_p,
    float* __restrict__ hub, int nchunk) {
  __shared__ float wacc[BLK / 64][GSZ];

  float L0 = L0_p[0], A = A_p[0], alpha = alpha_p[0], B = B_p[0];
  float beta = beta_p[0];
  float nb = -beta;

  int c0 = blockIdx.x;
  int c1 = nchunk - 1 - c0;

  if (beta == 0.5f) {
    process_chunk<true>(c0, S1, step, loss, lrs, cpw, dd, gapp,
                        L0, A, alpha, B, nb, wacc, hub);
    if (c1 != c0)
      process_chunk<true>(c1, S1, step, loss, lrs, cpw, dd, gapp,
                          L0, A, alpha, B, nb, wacc, hub);
  } else {
    process_chunk<false>(c0, S1, step, loss, lrs, cpw, dd, gapp,
                         L0, A, alpha, B, nb, wacc, hub);
    if (c1 != c0)
      process_chunk<false>(c1, S1, step, loss, lrs, cpw, dd, gapp,
                           L0, A, alpha, B, nb, wacc, hub);
  }
}

// ---------------------------------------------------------------------------
// Deterministic single-block reduction of hub[0..M) -> out[0]
// ---------------------------------------------------------------------------
__global__ __launch_bounds__(1024) void reduce_kernel(
    const float* __restrict__ hub, float* __restrict__ out, int M) {
  float acc = 0.0f;
  for (int i = threadIdx.x; i < M; i += 1024) acc += hub[i];
#pragma unroll
  for (int off = 32; off; off >>= 1) acc += __shfl_down(acc, off, 64);
  __shared__ float wacc[16];
  int lane = threadIdx.x & 63, wid = threadIdx.x >> 6;
  if (lane == 0) wacc[wid] = acc;
  __syncthreads();
  if (threadIdx.x == 0) {
    float t = 0.0f;
#pragma unroll
    for (int i = 0; i < 16; ++i) t += wacc[i];
    out[0] = t;
  }
}

extern "C" void kernel_launch(void* const* d_in, const int* in_sizes, int n_in,
                              void* d_out, int out_size, void* d_ws, size_t ws_size,
                              hipStream_t stream) {
  const float* S1      = (const float*)d_in[0];
  const float* lrs     = (const float*)d_in[1];
  const float* lr_sum  = (const float*)d_in[2];
  const int*   step    = (const int*)  d_in[3];
  const float* lr_gap  = (const float*)d_in[4];
  const float* loss    = (const float*)d_in[5];
  const float* L0_p    = (const float*)d_in[6];
  const float* A_p     = (const float*)d_in[7];
  const float* alpha_p = (const float*)d_in[8];
  const float* B_p     = (const float*)d_in[9];
  const float* C_p     = (const float*)d_in[10];
  const float* beta_p  = (const float*)d_in[11];
  const float* gamma_p = (const float*)d_in[12];

  int M = in_sizes[0];
  int T = in_sizes[1];
  int Tp = T + PAD;  // (T+PAD)*4 bytes stays 16B-aligned for T=16384

  float* cpw  = (float*)d_ws;   // Tp floats
  float* dd   = cpw + Tp;       // Tp floats
  float* gapp = dd + Tp;        // Tp floats
  float* hub  = gapp + Tp;      // M floats

  int nchunk = M / GSZ;                 // 1024
  int nblocks = (nchunk + 1) / 2;       // 512, paired chunks

  precompute_kernel<<<(Tp + 255) / 256, 256, 0, stream>>>(
      lrs, lr_sum, lr_gap, cpw, dd, gapp, gamma_p, C_p, T);
  ld_kernel<<<nblocks, BLK, 0, stream>>>(
      S1, step, loss, lrs, cpw, dd, gapp,
      L0_p, A_p, alpha_p, B_p, beta_p, hub, nchunk);
  reduce_kernel<<<1, 1024, 0, stream>>>(hub, (float*)d_out, M);
}

// Round 7
// 26.898 us; speedup vs baseline: 2.0058x; 2.0058x over previous
//
#include <hip/hip_runtime.h>
#include <math.h>

#define BLK 512         // threads per block (8 waves)
#define GSZ 8           // checkpoints (m values) per chunk/block
#define PAD 4           // float4-overrun padding on k-arrays
#define KSTRIDE (BLK*4) // elements covered per loop sweep (2048)

#if __has_builtin(__builtin_amdgcn_rsqf)
#define RSQF(x) __builtin_amdgcn_rsqf(x)
#else
#define RSQF(x) (1.0f / sqrtf(x))
#endif

// fast x^e for x>0 via hw exp2/log2 (~1e-6 rel err, vs 0.176 abs budget)
__device__ __forceinline__ float fast_pow(float x, float e) {
  return __expf(e * __logf(x));
}

// ---------------------------------------------------------------------------
// Precompute (T+PAD elements):
//   cpw[k] = C * lrs[k]^(-gamma)          (k>=1)
//   dd[k]  = 1 - cpw[k]*lr_sum[k-1]       so inner = fma(cpw, Ssum, dd)
//   gapp[k] = lr_gap[k]                   (padded copy, zero beyond T)
// ---------------------------------------------------------------------------
__global__ __launch_bounds__(256) void precompute_kernel(
    const float* __restrict__ lrs, const float* __restrict__ lr_sum,
    const float* __restrict__ lr_gap,
    float* __restrict__ cpw, float* __restrict__ dd, float* __restrict__ gapp,
    const float* __restrict__ gamma_p, const float* __restrict__ C_p, int T) {
  int i = blockIdx.x * 256 + threadIdx.x;
  if (i >= T + PAD) return;
  if (i == 0 || i >= T) {
    cpw[i] = 0.0f; dd[i] = 1.0f; gapp[i] = 0.0f;
    return;
  }
  float c = C_p[0] * fast_pow(lrs[i], -gamma_p[0]);
  cpw[i]  = c;
  dd[i]   = fmaf(-c, lr_sum[i - 1], 1.0f);
  gapp[i] = lr_gap[i];
}

// ---------------------------------------------------------------------------
// Inner body: acc[j] += sum_k gapp[k] * inner(k, Ss[j])^-beta over one chunk.
// Phase 1 unmasked (k <= smin guaranteed, inner >= 1); phase 2 masked —
// select on p AFTER the transcendental (0*NaN poison, round-2 bug).
// ---------------------------------------------------------------------------
template <bool USE_RSQ>
__device__ __forceinline__ void ld_body(
    const float* __restrict__ cpw, const float* __restrict__ dd,
    const float* __restrict__ gapp,
    const float (&Ss)[GSZ], const int (&sv)[GSZ], float (&acc)[GSZ],
    int kEnd1, int smax, float nb) {
  int tid = threadIdx.x;

  for (int k0 = tid * 4; k0 < kEnd1; k0 += KSTRIDE) {
    float4 c4 = *(const float4*)(cpw + k0);
    float4 d4 = *(const float4*)(dd + k0);
    float4 g4 = *(const float4*)(gapp + k0);
    const float ce[4] = {c4.x, c4.y, c4.z, c4.w};
    const float de[4] = {d4.x, d4.y, d4.z, d4.w};
    const float ge[4] = {g4.x, g4.y, g4.z, g4.w};
#pragma unroll
    for (int e = 0; e < 4; ++e) {
#pragma unroll
      for (int j = 0; j < GSZ; ++j) {
        float inner = fmaf(ce[e], Ss[j], de[e]);   // >= 1 here
        float p = USE_RSQ ? RSQF(inner) : __expf(nb * __logf(inner));
        acc[j] = fmaf(ge[e], p, acc[j]);
      }
    }
  }

  for (int k0 = kEnd1 + tid * 4; k0 <= smax; k0 += KSTRIDE) {
    // safe: arrays padded to T+PAD, k0 <= smax <= T-1
    float4 c4 = *(const float4*)(cpw + k0);
    float4 d4 = *(const float4*)(dd + k0);
    float4 g4 = *(const float4*)(gapp + k0);
    const float ce[4] = {c4.x, c4.y, c4.z, c4.w};
    const float de[4] = {d4.x, d4.y, d4.z, d4.w};
    const float ge[4] = {g4.x, g4.y, g4.z, g4.w};
#pragma unroll
    for (int e = 0; e < 4; ++e) {
#pragma unroll
      for (int j = 0; j < GSZ; ++j) {
        float inner = fmaf(ce[e], Ss[j], de[e]);   // may be <= 0 if masked
        float p = USE_RSQ ? RSQF(inner) : __expf(nb * __logf(inner));
        float pm = (k0 + e <= sv[j]) ? p : 0.0f;   // select AFTER computing p
        acc[j] = fmaf(ge[e], pm, acc[j]);
      }
    }
  }
}

// ---------------------------------------------------------------------------
// Main: ONE chunk (GSZ checkpoints) per block. 1024 blocks x 8 waves =
// 8192 waves = 32 waves/CU (hw max) -> 4 independent blocks/CU to hide
// L2 latency and barrier convoys (R6 diagnosis: 16us non-inner stall time
// at 16 waves/CU). launch_bounds(512,8) caps VGPR at 64 (we use ~44).
// ---------------------------------------------------------------------------
__global__ __launch_bounds__(BLK, 8) void ld_kernel(
    const float* __restrict__ S1, const int* __restrict__ step,
    const float* __restrict__ loss, const float* __restrict__ lrs,
    const float* __restrict__ cpw, const float* __restrict__ dd,
    const float* __restrict__ gapp,
    const float* __restrict__ L0_p, const float* __restrict__ A_p,
    const float* __restrict__ alpha_p, const float* __restrict__ B_p,
    const float* __restrict__ beta_p,
    float* __restrict__ hub, int nchunk) {
  __shared__ float wacc[BLK / 64][GSZ];

  int mbase = blockIdx.x * GSZ;

  float Ss[GSZ]; int sv[GSZ]; float acc[GSZ];
#pragma unroll
  for (int j = 0; j < GSZ; ++j) {
    Ss[j] = S1[mbase + j];
    sv[j] = step[mbase + j];
    acc[j] = 0.0f;
  }
  int smin = sv[0], smax = sv[0];
#pragma unroll
  for (int j = 1; j < GSZ; ++j) {
    smin = min(smin, sv[j]);
    smax = max(smax, sv[j]);
  }
  int kEnd1 = ((smin + 1) / KSTRIDE) * KSTRIDE;

  float beta = beta_p[0];
  float nb = -beta;

  if (beta == 0.5f)
    ld_body<true>(cpw, dd, gapp, Ss, sv, acc, kEnd1, smax, nb);
  else
    ld_body<false>(cpw, dd, gapp, Ss, sv, acc, kEnd1, smax, nb);

  // block reduction: 64-lane shuffle, then across the 8 waves via LDS
  int lane = threadIdx.x & 63, wid = threadIdx.x >> 6;
#pragma unroll
  for (int j = 0; j < GSZ; ++j) {
    float v = acc[j];
#pragma unroll
    for (int off = 32; off; off >>= 1) v += __shfl_down(v, off, 64);
    if (lane == 0) wacc[wid][j] = v;
  }
  __syncthreads();

  if (threadIdx.x < GSZ) {
    int j = threadIdx.x;
    int m = mbase + j;
    float sgp = 0.0f;
#pragma unroll
    for (int w = 0; w < BLK / 64; ++w) sgp += wacc[w][j];
    int s = step[m];
    float Ssum = S1[m];
    float LD = (lrs[0] - lrs[s]) - sgp;   // telescoped gap sum
    float pred = L0_p[0] + A_p[0] * fast_pow(Ssum, -alpha_p[0]) + B_p[0] * LD;
    pred = fmaxf(pred, 1e-10f);
    float r = __logf(loss[m]) - __logf(pred);
    float a = fabsf(r);
    const float dlt = 0.001f;
    hub[m] = (a <= dlt) ? (0.5f * r * r) : (dlt * (a - 0.5f * dlt));
  }
}

// ---------------------------------------------------------------------------
// Deterministic single-block reduction of hub[0..M) -> out[0]
// ---------------------------------------------------------------------------
__global__ __launch_bounds__(1024) void reduce_kernel(
    const float* __restrict__ hub, float* __restrict__ out, int M) {
  float acc = 0.0f;
  for (int i = threadIdx.x; i < M; i += 1024) acc += hub[i];
#pragma unroll
  for (int off = 32; off; off >>= 1) acc += __shfl_down(acc, off, 64);
  __shared__ float wacc[16];
  int lane = threadIdx.x & 63, wid = threadIdx.x >> 6;
  if (lane == 0) wacc[wid] = acc;
  __syncthreads();
  if (threadIdx.x == 0) {
    float t = 0.0f;
#pragma unroll
    for (int i = 0; i < 16; ++i) t += wacc[i];
    out[0] = t;
  }
}

extern "C" void kernel_launch(void* const* d_in, const int* in_sizes, int n_in,
                              void* d_out, int out_size, void* d_ws, size_t ws_size,
                              hipStream_t stream) {
  const float* S1      = (const float*)d_in[0];
  const float* lrs     = (const float*)d_in[1];
  const float* lr_sum  = (const float*)d_in[2];
  const int*   step    = (const int*)  d_in[3];
  const float* lr_gap  = (const float*)d_in[4];
  const float* loss    = (const float*)d_in[5];
  const float* L0_p    = (const float*)d_in[6];
  const float* A_p     = (const float*)d_in[7];
  const float* alpha_p = (const float*)d_in[8];
  const float* B_p     = (const float*)d_in[9];
  const float* C_p     = (const float*)d_in[10];
  const float* beta_p  = (const float*)d_in[11];
  const float* gamma_p = (const float*)d_in[12];

  int M = in_sizes[0];
  int T = in_sizes[1];
  int Tp = T + PAD;  // (T+PAD)*4 bytes stays 16B-aligned for T=16384

  float* cpw  = (float*)d_ws;   // Tp floats
  float* dd   = cpw + Tp;       // Tp floats
  float* gapp = dd + Tp;        // Tp floats
  float* hub  = gapp + Tp;      // M floats

  int nchunk = M / GSZ;         // 1024 blocks, one chunk each

  precompute_kernel<<<(Tp + 255) / 256, 256, 0, stream>>>(
      lrs, lr_sum, lr_gap, cpw, dd, gapp, gamma_p, C_p, T);
  ld_kernel<<<nchunk, BLK, 0, stream>>>(
      S1, step, loss, lrs, cpw, dd, gapp,
      L0_p, A_p, alpha_p, B_p, beta_p, hub, nchunk);
  reduce_kernel<<<1, 1024, 0, stream>>>(hub, (float*)d_out, M);
}